// Round 2
// baseline (181.795 us; speedup 1.0000x reference)
//
#include <hip/hip_runtime.h>
#include <hip/hip_fp16.h>
#include <math.h>

// ShadowMapping forward: hard + soft (Fourier-basis, blurred) shadow maps.
// R2: geometry dot products now use SEQUENTIAL FMA over the contraction index
//     (XLA DotOpEmitter emits llvm.fmuladd; elementwise ops stay uncontracted).
//     Everything else identical to R1 (contract off, radius-2 Gaussian,
//     fp16 D_map packed with zg into 32B records).

#define RESN 512
#define NL 16
#define NPIX (RESN*RESN)
#define BT 16
#define BH 20  // BT + 2*2 halo

struct LightParams {            // 64 B
  float e00, e02, e10, e11, e12, e20, e21, e22;
  float w[5];
  float pad[3];
};

__global__ void setup_kernel(const float* __restrict__ als,
                             LightParams* __restrict__ lp) {
  #pragma clang fp contract(off)
  int l = (int)threadIdx.x;
  if (l >= NL) return;
  float xd = als[l*7+0], yd = als[l*7+1], zd = als[l*7+2], sg = als[l*7+3];
  float cosp = sqrtf(xd*xd + zd*zd);   // elementwise: plain rounded ops
  float cost = zd / cosp;
  float sint = xd / cosp;
  LightParams p;
  p.e00 = cost;               // mv row0 = [cost, 0, -sint, 0]
  p.e02 = -sint;
  p.e10 = (-sint) * yd;       // mv row1 = [-sint*yd, cosp, -cost*yd, 0]
  p.e11 = cosp;
  p.e12 = (-cost) * yd;
  p.e20 = cosp * sint;        // mv row2 = [cosp*sint, yd, cosp*cost, -2.7]
  p.e21 = yd;
  p.e22 = cosp * cost;
  // sig = (res/RES_OPT*(6*s+1)-1)/6 with res/RES_OPT = 2.0
  float sig = ((2.0f * (6.0f * sg + 1.0f)) - 1.0f) / 6.0f;
  float ksum = 0.0f;
  float kmid[5];
  for (int i = 0; i < 21; ++i) {
    float t = (float)(i - 10);
    float r = t / sig;
    float e = expf(-0.5f * (r * r));
    ksum += e;
    if (i >= 8 && i <= 12) kmid[i-8] = e;
  }
  for (int k = 0; k < 5; ++k) p.w[k] = kmid[k] / ksum;
  p.pad[0] = p.pad[1] = p.pad[2] = 0.0f;
  lp[l] = p;
}

// Builds blurred basis D (8 ch, fp16) per shadow texel; packed=1 also embeds
// zg (fp32) so the main kernel does a single scattered gather per (l,pixel).
__global__ __launch_bounds__(256) void build_kernel(
    const float* __restrict__ z_map,
    const LightParams* __restrict__ lpg,
    uint4* __restrict__ dmap, int packed)
{
  __shared__ float sc[8][BH*BH];   // sincos fields over halo tile
  __shared__ float vb[8][BT*BH];   // vertically blurred
  const int l = (int)blockIdx.z;
  const int by = (int)blockIdx.y * BT, bx = (int)blockIdx.x * BT;
  const int tid = (int)threadIdx.x;
  const LightParams P = lpg[l];
  const float CK[4] = { (float)(3.141592653589793),
                        (float)(3.0*3.141592653589793),
                        (float)(5.0*3.141592653589793),
                        (float)(7.0*3.141592653589793) };
  for (int i = tid; i < BH*BH; i += 256) {
    int hy = by + i / BH - 2;
    int hx = bx + i % BH - 2;
    float v[8] = {0,0,0,0,0,0,0,0};  // zero padding outside image
    if (hy >= 0 && hy < RESN && hx >= 0 && hx < RESN) {
      float z = z_map[(l<<18) + (hy<<9) + hx];
      #pragma unroll
      for (int m = 0; m < 4; ++m) {
        float s, c;
        sincosf(CK[m]*z, &s, &c);
        v[2*m] = c; v[2*m+1] = s;
      }
    }
    #pragma unroll
    for (int ch = 0; ch < 8; ++ch) sc[ch][i] = v[ch];
  }
  __syncthreads();
  for (int j = tid; j < BT*BH; j += 256) {
    int y = j / BH, hx = j - y*BH;
    #pragma unroll
    for (int ch = 0; ch < 8; ++ch) {
      float acc = P.w[0]*sc[ch][(y+0)*BH+hx];
      acc += P.w[1]*sc[ch][(y+1)*BH+hx];
      acc += P.w[2]*sc[ch][(y+2)*BH+hx];
      acc += P.w[3]*sc[ch][(y+3)*BH+hx];
      acc += P.w[4]*sc[ch][(y+4)*BH+hx];
      vb[ch][j] = acc;
    }
  }
  __syncthreads();
  {
    int y = tid >> 4, x = tid & 15;
    union { __half h[8]; uint32_t u[4]; } pk;
    #pragma unroll
    for (int ch = 0; ch < 8; ++ch) {
      float acc = P.w[0]*vb[ch][y*BH + x];
      acc += P.w[1]*vb[ch][y*BH + x+1];
      acc += P.w[2]*vb[ch][y*BH + x+2];
      acc += P.w[3]*vb[ch][y*BH + x+3];
      acc += P.w[4]*vb[ch][y*BH + x+4];
      pk.h[ch] = __float2half(acc);
    }
    int gy = by + y, gx = bx + x;
    size_t idx = (size_t)((l<<18) + (gy<<9) + gx);
    if (packed) {
      float zg = z_map[idx];
      dmap[idx*2]   = make_uint4(__float_as_uint(zg), pk.u[0], pk.u[1], pk.u[2]);
      dmap[idx*2+1] = make_uint4(pk.u[3], 0u, 0u, 0u);
    } else {
      dmap[idx] = make_uint4(pk.u[0], pk.u[1], pk.u[2], pk.u[3]);
    }
  }
}

__device__ inline void unp2(uint32_t u, float& a, float& b) {
  union { uint32_t u; __half h[2]; } t; t.u = u;
  a = __half2float(t.h[0]);
  b = __half2float(t.h[1]);
}

__global__ __launch_bounds__(256) void main_kernel(
    const float* __restrict__ depth,
    const float* __restrict__ mask,
    const float* __restrict__ z_map,
    const LightParams* __restrict__ lpg,
    const uint4* __restrict__ dmap,
    float* __restrict__ out,
    float TANHF, float OZF, float OWF, int mode)
{
  #pragma clang fp contract(off)
  __shared__ float lps[NL*16];
  lps[threadIdx.x] = ((const float*)lpg)[threadIdx.x];
  __syncthreads();
  const float CK[4] = { (float)(3.141592653589793),
                        (float)(3.0*3.141592653589793),
                        (float)(5.0*3.141592653589793),
                        (float)(7.0*3.141592653589793) };
  const float OFFS = -0.0642233295781f;
  const float CLB  = 0.4458709375254f;
  int p = (int)blockIdx.x * 256 + (int)threadIdx.x;
  int r = p >> 9, c = p & 511;
  float dz = depth[p];
  float mk = mask[p];
  // m1 values are exact in f32 (all ops exact for these inputs)
  float m1c = 2.0f * ((float)c / 512.0f + 0.0009765625f) - 1.0f;
  float m1r = 2.0f * ((float)r / 512.0f + 0.0009765625f) - 1.0f;
  float tT = dz * TANHF;    // px = (-dz*T)*m1c => qx=-px=(dz*T)*m1c exactly
  float qx = tT * m1c;
  float qy = tT * m1r;
  float qz = 2.7f - dz;     // posw_c.z = f32(2.7 - dz), order-robust
  for (int l = 0; l < NL; ++l) {
    const float* P = &lps[l*16];
    // XLA dot emitter: sequential fmuladd over w (w=0:qx, w=1:qy, w=2:qz,
    // w=3: constant term added plainly since fma(1,c,acc)=acc+c).
    float X1 = fmaf(qz, P[1], qx * P[0]);                 // qy coeff is 0
    float Y1 = fmaf(qz, P[4], fmaf(qy, P[3], qx * P[2]));
    float T2 = fmaf(qz, P[7], fmaf(qy, P[6], qx * P[5]));
    float Z1 = T2 + (-2.7f);
    float ZZ = (Z1 * OZF) + OWF;    // second einsum: r(r(t2*oz)+ow), no fma
    float uf = (X1 + 1.0f) * 256.0f;   // (512*(X+1))*0.5, pow2 muls exact
    float vf = (Y1 + 1.0f) * 256.0f;
    int u = (int)uf; u = u < 0 ? 0 : (u > 511 ? 511 : u);
    int v = (int)vf; v = v < 0 ? 0 : (v > 511 ? 511 : v);
    float dd = 0.5f * (1.0f + ZZ);
    dd = fminf(fmaxf(dd, 0.0f), 1.0f);
    int zi = (l<<18) + (v<<9) + u;
    float zg;
    float q = 0.0f;
    float dpo = dd + OFFS;
    if (mode == 2) {
      // fallback: direct 25-tap using sum_n a_n B_n = sum_m (2/ck) sin(ck(z-c))
      zg = z_map[zi];
      float wv[5] = {P[8], P[9], P[10], P[11], P[12]};
      for (int ty = -2; ty <= 2; ++ty) {
        int yy = v + ty; if (yy < 0 || yy >= RESN) continue;
        for (int tx = -2; tx <= 2; ++tx) {
          int xx = u + tx; if (xx < 0 || xx >= RESN) continue;
          float z = z_map[(l<<18)+(yy<<9)+xx];
          float w = wv[ty+2]*wv[tx+2];
          float acc = 0.0f;
          #pragma unroll
          for (int m = 0; m < 4; ++m)
            acc += (2.0f/CK[m]) * sinf(CK[m]*(z - dpo));
          q += w * acc;
        }
      }
    } else {
      float D[8];
      if (mode == 0) {
        uint4 w0 = dmap[(size_t)zi*2];
        uint32_t w4 = ((const uint32_t*)dmap)[(size_t)zi*8 + 4];
        zg = __uint_as_float(w0.x);
        unp2(w0.y, D[0], D[1]);
        unp2(w0.z, D[2], D[3]);
        unp2(w0.w, D[4], D[5]);
        unp2(w4,   D[6], D[7]);
      } else {
        zg = z_map[zi];
        uint4 w = dmap[zi];
        unp2(w.x, D[0], D[1]);
        unp2(w.y, D[2], D[3]);
        unp2(w.z, D[4], D[5]);
        unp2(w.w, D[6], D[7]);
      }
      #pragma unroll
      for (int m = 0; m < 4; ++m) {
        float s, cc;
        sincosf(CK[m]*dpo, &s, &cc);
        float ae = (-2.0f * s) / CK[m];
        float ao = ( 2.0f * cc) / CK[m];
        q += ae * D[2*m] + ao * D[2*m+1];
      }
    }
    float diff = fmaxf(dd - zg, 0.0f);
    float hard = (diff > 0.008f) ? 0.0f : 1.0f;
    out[(l<<18) + p] = mk * hard;
    float qc = fminf(fmaxf(q, -CLB), CLB) / CLB;
    float sf = 0.5f * (qc + 1.0f);
    sf = fminf(fmaxf(sf, 0.0f), 1.0f);
    out[(NL<<18) + (l<<18) + p] = mk * sf;
  }
}

extern "C" void kernel_launch(void* const* d_in, const int* in_sizes, int n_in,
                              void* d_out, int out_size, void* d_ws, size_t ws_size,
                              hipStream_t stream) {
  (void)in_sizes; (void)n_in; (void)out_size;
  const float* depth = (const float*)d_in[0];
  const float* als   = (const float*)d_in[1];
  const float* mask  = (const float*)d_in[2];
  const float* z_map = (const float*)d_in[3];
  float* out = (float*)d_out;
  LightParams* lp = (LightParams*)d_ws;               // 16 * 64 B = 1024 B
  uint4* dmap = (uint4*)((char*)d_ws + 1024);
  // constants in double, replicating numpy, then rounded to f32
  double TANH = tan(2.0*atan(0.5*36.0/50.0)/2.0);
  double NEARc = 2.7 - sqrt(2.0)*2.7*TANH;
  double FARc  = 2.7 + sqrt(2.0)*2.7*TANH;
  float ozf = (float)(-2.0/(FARc-NEARc));
  float owf = (float)((-(FARc+NEARc))/(FARc-NEARc));
  float tanhf_ = (float)TANH;
  size_t need_packed = 1024 + (size_t)NL*NPIX*32;
  size_t need_half   = 1024 + (size_t)NL*NPIX*16;
  int mode = (ws_size >= need_packed) ? 0 : ((ws_size >= need_half) ? 1 : 2);

  setup_kernel<<<1, 64, 0, stream>>>(als, lp);
  if (mode != 2) {
    dim3 gB(RESN/BT, RESN/BT, NL);
    build_kernel<<<gB, 256, 0, stream>>>(z_map, lp, dmap, mode == 0 ? 1 : 0);
  }
  main_kernel<<<NPIX/256, 256, 0, stream>>>(depth, mask, z_map, lp, dmap, out,
                                            tanhf_, ozf, owf, mode);
}

// Round 3
// 153.601 us; speedup vs baseline: 1.1836x; 1.1836x over previous
//
#include <hip/hip_runtime.h>
#include <hip/hip_fp16.h>
#include <math.h>

// ShadowMapping forward: hard + soft (Fourier-basis, blurred) shadow maps.
// R3: build = float4 LDS (b128) separable blur, 1 sincos + harmonic recurrence,
//     16B fp16 records (67MB). main = per-(light,block) grid for 4x TLP,
//     16B+4B gathers, 1 sincos + recurrence. Geometry FMA chain bit-identical
//     to R2 (validated: XLA dot emitter = sequential fmuladd over w).

#define RESN 512
#define NL 16
#define NPIX (RESN*RESN)
#define BT 16
#define BH 20  // BT + 2*2 halo

struct LightParams {            // 64 B
  float e00, e02, e10, e11, e12, e20, e21, e22;
  float w[5];
  float pad[3];
};

__global__ void setup_kernel(const float* __restrict__ als,
                             LightParams* __restrict__ lp) {
  #pragma clang fp contract(off)
  int l = (int)threadIdx.x;
  if (l >= NL) return;
  float xd = als[l*7+0], yd = als[l*7+1], zd = als[l*7+2], sg = als[l*7+3];
  float cosp = sqrtf(xd*xd + zd*zd);   // elementwise: plain rounded ops
  float cost = zd / cosp;
  float sint = xd / cosp;
  LightParams p;
  p.e00 = cost;               // mv row0 = [cost, 0, -sint, 0]
  p.e02 = -sint;
  p.e10 = (-sint) * yd;       // mv row1 = [-sint*yd, cosp, -cost*yd, 0]
  p.e11 = cosp;
  p.e12 = (-cost) * yd;
  p.e20 = cosp * sint;        // mv row2 = [cosp*sint, yd, cosp*cost, -2.7]
  p.e21 = yd;
  p.e22 = cosp * cost;
  // sig = (res/RES_OPT*(6*s+1)-1)/6 with res/RES_OPT = 2.0
  float sig = ((2.0f * (6.0f * sg + 1.0f)) - 1.0f) / 6.0f;
  float ksum = 0.0f;
  float kmid[5];
  for (int i = 0; i < 21; ++i) {
    float t = (float)(i - 10);
    float r = t / sig;
    float e = expf(-0.5f * (r * r));
    ksum += e;
    if (i >= 8 && i <= 12) kmid[i-8] = e;
  }
  for (int k = 0; k < 5; ++k) p.w[k] = kmid[k] / ksum;
  p.pad[0] = p.pad[1] = p.pad[2] = 0.0f;
  lp[l] = p;
}

// sincos(pi*x·{1,3,5,7}) from one sincos via angle addition.
// s1=c1=0 input (zero padding) propagates 0 to all output channels.
__device__ inline void harm8(float s1, float c1,
                             float& c3, float& s3, float& c5, float& s5,
                             float& c7, float& s7) {
  float s2 = 2.0f*s1*c1;
  float c2 = 1.0f - 2.0f*s1*s1;
  s3 = s2*c1 + c2*s1;  c3 = c2*c1 - s2*s1;
  s5 = s3*c2 + c3*s2;  c5 = c3*c2 - s3*s2;
  s7 = s5*c2 + c5*s2;  c7 = c5*c2 - s5*s2;
}

// Blurred basis D (8 ch fp16, 16B/texel). LDS in texel-major float4 pairs so
// every LDS access is a contiguous b128 (build was LDS-bound in R2).
__global__ __launch_bounds__(256) void build_kernel(
    const float* __restrict__ z_map,
    const LightParams* __restrict__ lpg,
    uint4* __restrict__ dmap)
{
  __shared__ float4 scA[BH*BH], scB[BH*BH];   // (c1,s1,c3,s3) / (c5,s5,c7,s7)
  __shared__ float4 vbA[BT*BH], vbB[BT*BH];   // vertically blurred
  const int l = (int)blockIdx.z;
  const int by = (int)blockIdx.y * BT, bx = (int)blockIdx.x * BT;
  const int tid = (int)threadIdx.x;
  const LightParams P = lpg[l];               // uniform -> scalar loads
  const float PI = 3.14159265358979323846f;
  for (int i = tid; i < BH*BH; i += 256) {
    int hy = by + i / BH - 2;
    int hx = bx + i % BH - 2;
    float s1 = 0.0f, c1 = 0.0f;               // zero pad outside image
    if (hy >= 0 && hy < RESN && hx >= 0 && hx < RESN) {
      float z = z_map[(l<<18) + (hy<<9) + hx];
      sincosf(PI*z, &s1, &c1);
    }
    float c3,s3,c5,s5,c7,s7;
    harm8(s1, c1, c3, s3, c5, s5, c7, s7);
    scA[i] = make_float4(c1, s1, c3, s3);
    scB[i] = make_float4(c5, s5, c7, s7);
  }
  __syncthreads();
  for (int j = tid; j < BT*BH; j += 256) {
    int y = j / BH, hx = j - y*BH;
    float4 a = make_float4(0,0,0,0), b = make_float4(0,0,0,0);
    #pragma unroll
    for (int t = 0; t < 5; ++t) {
      float w = P.w[t];
      float4 sa = scA[(y+t)*BH + hx];
      float4 sb = scB[(y+t)*BH + hx];
      a.x += w*sa.x; a.y += w*sa.y; a.z += w*sa.z; a.w += w*sa.w;
      b.x += w*sb.x; b.y += w*sb.y; b.z += w*sb.z; b.w += w*sb.w;
    }
    vbA[j] = a; vbB[j] = b;
  }
  __syncthreads();
  {
    int y = tid >> 4, x = tid & 15;
    float4 a = make_float4(0,0,0,0), b = make_float4(0,0,0,0);
    #pragma unroll
    for (int t = 0; t < 5; ++t) {
      float w = P.w[t];
      float4 sa = vbA[y*BH + x + t];
      float4 sb = vbB[y*BH + x + t];
      a.x += w*sa.x; a.y += w*sa.y; a.z += w*sa.z; a.w += w*sa.w;
      b.x += w*sb.x; b.y += w*sb.y; b.z += w*sb.z; b.w += w*sb.w;
    }
    union { __half h[8]; uint4 u; } pk;
    pk.h[0] = __float2half(a.x); pk.h[1] = __float2half(a.y);
    pk.h[2] = __float2half(a.z); pk.h[3] = __float2half(a.w);
    pk.h[4] = __float2half(b.x); pk.h[5] = __float2half(b.y);
    pk.h[6] = __float2half(b.z); pk.h[7] = __float2half(b.w);
    dmap[(l<<18) + ((by+y)<<9) + (bx+x)] = pk.u;
  }
}

__device__ inline void unp2(uint32_t u, float& a, float& b) {
  union { uint32_t u; __half h[2]; } t; t.u = u;
  a = __half2float(t.h[0]);
  b = __half2float(t.h[1]);
}

__global__ __launch_bounds__(256) void main_kernel(
    const float* __restrict__ depth,
    const float* __restrict__ mask,
    const float* __restrict__ z_map,
    const LightParams* __restrict__ lpg,
    const uint4* __restrict__ dmap,
    float* __restrict__ out,
    float TANHF, float OZF, float OWF, int mode)
{
  #pragma clang fp contract(off)
  const float CK1 = 3.14159265358979323846f;
  const float CK3 = (float)(3.0*3.141592653589793);
  const float CK5 = (float)(5.0*3.141592653589793);
  const float CK7 = (float)(7.0*3.141592653589793);
  const float OFFS = -0.0642233295781f;
  const float CLB  = 0.4458709375254f;
  const int l = (int)blockIdx.y;
  const int p = (int)blockIdx.x * 256 + (int)threadIdx.x;
  const int r = p >> 9, c = p & 511;
  const LightParams P = lpg[l];               // uniform -> scalar loads
  float dz = depth[p];
  float mk = mask[p];
  // m1 values are exact in f32 (all ops exact for these inputs)
  float m1c = 2.0f * ((float)c / 512.0f + 0.0009765625f) - 1.0f;
  float m1r = 2.0f * ((float)r / 512.0f + 0.0009765625f) - 1.0f;
  float tT = dz * TANHF;    // px = (-dz*T)*m1c => qx=-px=(dz*T)*m1c exactly
  float qx = tT * m1c;
  float qy = tT * m1r;
  float qz = 2.7f - dz;     // posw_c.z = f32(2.7 - dz), order-robust
  // XLA dot emitter: sequential fmuladd over w (validated in R2)
  float X1 = fmaf(qz, P.e02, qx * P.e00);                    // qy coeff is 0
  float Y1 = fmaf(qz, P.e12, fmaf(qy, P.e11, qx * P.e10));
  float T2 = fmaf(qz, P.e22, fmaf(qy, P.e21, qx * P.e20));
  float Z1 = T2 + (-2.7f);
  float ZZ = (Z1 * OZF) + OWF;    // second einsum: r(r(t2*oz)+ow), no fma
  float uf = (X1 + 1.0f) * 256.0f;   // (512*(X+1))*0.5, pow2 muls exact
  float vf = (Y1 + 1.0f) * 256.0f;
  int u = (int)uf; u = u < 0 ? 0 : (u > 511 ? 511 : u);
  int v = (int)vf; v = v < 0 ? 0 : (v > 511 ? 511 : v);
  float dd = 0.5f * (1.0f + ZZ);
  dd = fminf(fmaxf(dd, 0.0f), 1.0f);
  int zi = (l<<18) + (v<<9) + u;
  float dpo = dd + OFFS;
  float zg = z_map[zi];
  float q = 0.0f;
  if (mode == 2) {
    // fallback: direct 25-tap, sum_n a_n B_n = sum_m (2/ck) sin(ck(z-dpo))
    float wv[5] = {P.w[0], P.w[1], P.w[2], P.w[3], P.w[4]};
    for (int ty = -2; ty <= 2; ++ty) {
      int yy = v + ty; if (yy < 0 || yy >= RESN) continue;
      for (int tx = -2; tx <= 2; ++tx) {
        int xx = u + tx; if (xx < 0 || xx >= RESN) continue;
        float z = z_map[(l<<18)+(yy<<9)+xx];
        float w = wv[ty+2]*wv[tx+2];
        float acc = (2.0f/CK1) * sinf(CK1*(z - dpo));
        acc += (2.0f/CK3) * sinf(CK3*(z - dpo));
        acc += (2.0f/CK5) * sinf(CK5*(z - dpo));
        acc += (2.0f/CK7) * sinf(CK7*(z - dpo));
        q += w * acc;
      }
    }
  } else {
    uint4 w = dmap[zi];
    float D0,D1,D2,D3,D4,D5,D6,D7;
    unp2(w.x, D0, D1);
    unp2(w.y, D2, D3);
    unp2(w.z, D4, D5);
    unp2(w.w, D6, D7);
    float s1, c1;
    sincosf(CK1*dpo, &s1, &c1);
    float c3,s3,c5,s5,c7,s7;
    harm8(s1, c1, c3, s3, c5, s5, c7, s7);
    q  = (-2.0f*s1/CK1)*D0 + (2.0f*c1/CK1)*D1;
    q += (-2.0f*s3/CK3)*D2 + (2.0f*c3/CK3)*D3;
    q += (-2.0f*s5/CK5)*D4 + (2.0f*c5/CK5)*D5;
    q += (-2.0f*s7/CK7)*D6 + (2.0f*c7/CK7)*D7;
  }
  float diff = fmaxf(dd - zg, 0.0f);
  float hard = (diff > 0.008f) ? 0.0f : 1.0f;
  out[(l<<18) + p] = mk * hard;
  float qc = fminf(fmaxf(q, -CLB), CLB) / CLB;
  float sf = 0.5f * (qc + 1.0f);
  sf = fminf(fmaxf(sf, 0.0f), 1.0f);
  out[(NL<<18) + (l<<18) + p] = mk * sf;
}

extern "C" void kernel_launch(void* const* d_in, const int* in_sizes, int n_in,
                              void* d_out, int out_size, void* d_ws, size_t ws_size,
                              hipStream_t stream) {
  (void)in_sizes; (void)n_in; (void)out_size;
  const float* depth = (const float*)d_in[0];
  const float* als   = (const float*)d_in[1];
  const float* mask  = (const float*)d_in[2];
  const float* z_map = (const float*)d_in[3];
  float* out = (float*)d_out;
  LightParams* lp = (LightParams*)d_ws;               // 16 * 64 B = 1024 B
  uint4* dmap = (uint4*)((char*)d_ws + 1024);
  // constants in double, replicating numpy, then rounded to f32
  double TANH = tan(2.0*atan(0.5*36.0/50.0)/2.0);
  double NEARc = 2.7 - sqrt(2.0)*2.7*TANH;
  double FARc  = 2.7 + sqrt(2.0)*2.7*TANH;
  float ozf = (float)(-2.0/(FARc-NEARc));
  float owf = (float)((-(FARc+NEARc))/(FARc-NEARc));
  float tanhf_ = (float)TANH;
  size_t need = 1024 + (size_t)NL*NPIX*16;
  int mode = (ws_size >= need) ? 1 : 2;

  setup_kernel<<<1, 64, 0, stream>>>(als, lp);
  if (mode != 2) {
    dim3 gB(RESN/BT, RESN/BT, NL);
    build_kernel<<<gB, 256, 0, stream>>>(z_map, lp, dmap);
  }
  dim3 gM(NPIX/256, NL);
  main_kernel<<<gM, 256, 0, stream>>>(depth, mask, z_map, lp, dmap, out,
                                      tanhf_, ozf, owf, mode);
}